// Round 1
// baseline (4000.156 us; speedup 1.0000x reference)
//
#include <hip/hip_runtime.h>
#include <math.h>

// LSTM autoencoder, fully fused: one block per 8-sample batch tile, no grid
// sync (batch rows are independent recurrences). 256 blocks x 512 threads.
//
// Phases per encoder step t: z1 = xz1 + h1@Wr1 (512 cols, 1 col/thread,
// 8 batch rows unrolled per weight load) -> cell1+BN1 -> z2 (256 cols x
// 4 batch rows/thread) -> cell2. Decoder: z3 -> cell3+BN3 -> z4 -> cell4+BN4
// -> dense heads. Weights stream from L2 each step (coalesced row reads);
// h/c state lives in LDS (broadcast reads, conflict-free).

#define BATCH 2048
#define BT 8      // batch tile per block
#define TT 128    // timesteps
#define NF 8      // features
#define UO 128    // outer LSTM units
#define UI 64     // inner LSTM units
#define G1 512    // 4*UO
#define G2 256    // 4*UI
#define NTHREADS 512

__device__ __forceinline__ float sigmoid_(float x) {
    return 1.0f / (1.0f + __expf(-x));
}

__device__ __forceinline__ float selu_(float x) {
    const float alpha = 1.6732632423543772f;
    const float scale = 1.0507009873554805f;
    return x > 0.0f ? scale * x : scale * alpha * (__expf(x) - 1.0f);
}

__global__ __launch_bounds__(NTHREADS) void lstm_ae_kernel(
    const float* __restrict__ x,
    const float* __restrict__ Wk1, const float* __restrict__ Wr1, const float* __restrict__ b1,
    const float* __restrict__ g1, const float* __restrict__ be1, const float* __restrict__ m1, const float* __restrict__ v1,
    const float* __restrict__ Wk2, const float* __restrict__ Wr2, const float* __restrict__ b2,
    const float* __restrict__ g2, const float* __restrict__ be2, const float* __restrict__ m2, const float* __restrict__ v2,
    const float* __restrict__ Wk3, const float* __restrict__ Wr3, const float* __restrict__ b3,
    const float* __restrict__ g3, const float* __restrict__ be3, const float* __restrict__ m3, const float* __restrict__ v3,
    const float* __restrict__ Wk4, const float* __restrict__ Wr4, const float* __restrict__ b4,
    const float* __restrict__ g4, const float* __restrict__ be4, const float* __restrict__ m4, const float* __restrict__ v4,
    const float* __restrict__ Wd, const float* __restrict__ bd,
    float* __restrict__ out)
{
    __shared__ float h1[BT][UO], c1[BT][UO], h1b[BT][UO];
    __shared__ float h2[BT][UI], c2[BT][UI];
    __shared__ float xz3[BT][G2];
    __shared__ float h3[BT][UI], c3[BT][UI], h3b[BT][UI];
    __shared__ float h4[BT][UO], c4[BT][UO], h4b[BT][UO];
    __shared__ float z[BT][G1];
    __shared__ float xl[BT][NF];
    __shared__ float s1[UO], t1[UO], s2[UI], t2[UI], s3[UI], t3[UI], s4[UO], t4[UO];
    __shared__ float encb[BT][UI];

    const int tid = threadIdx.x;
    const int b0 = blockIdx.x * BT;

    // BN scale/shift precompute: y = h*s + t
    if (tid < UO) {
        float s = g1[tid] * rsqrtf(v1[tid] + 1e-3f);
        s1[tid] = s; t1[tid] = be1[tid] - m1[tid] * s;
        float s4v = g4[tid] * rsqrtf(v4[tid] + 1e-3f);
        s4[tid] = s4v; t4[tid] = be4[tid] - m4[tid] * s4v;
    } else if (tid < UO + UI) {
        int v_ = tid - UO;
        float s = g2[v_] * rsqrtf(v2[v_] + 1e-3f);
        s2[v_] = s; t2[v_] = be2[v_] - m2[v_] * s;
        float s3v = g3[v_] * rsqrtf(v3[v_] + 1e-3f);
        s3[v_] = s3v; t3[v_] = be3[v_] - m3[v_] * s3v;
    }
    // zero recurrent state
    for (int k = tid; k < BT * UO; k += NTHREADS) {
        int b = k >> 7, u = k & 127;
        h1[b][u] = 0.0f; c1[b][u] = 0.0f; h4[b][u] = 0.0f; c4[b][u] = 0.0f;
    }
    {
        int b = tid >> 6, v_ = tid & 63;
        h2[b][v_] = 0.0f; c2[b][v_] = 0.0f; h3[b][v_] = 0.0f; c3[b][v_] = 0.0f;
    }
    __syncthreads();

    // ===================== encoder =====================
    for (int t = 0; t < TT; ++t) {
        if (tid < BT * NF) {
            int b = tid >> 3, f = tid & 7;
            xl[b][f] = x[(size_t)(b0 + b) * TT * NF + (size_t)t * NF + f];
        }
        __syncthreads();

        // z1[b][j] = b1[j] + x@Wk1 + h1@Wr1   (one column j per thread)
        {
            const int j = tid;
            float wk[NF];
            #pragma unroll
            for (int f = 0; f < NF; ++f) wk[f] = Wk1[f * G1 + j];
            float bias = b1[j];
            float a[BT];
            #pragma unroll
            for (int b = 0; b < BT; ++b) {
                float s = bias;
                #pragma unroll
                for (int f = 0; f < NF; ++f) s += xl[b][f] * wk[f];
                a[b] = s;
            }
            #pragma unroll 4
            for (int u = 0; u < UO; ++u) {
                float w = Wr1[u * G1 + j];
                #pragma unroll
                for (int b = 0; b < BT; ++b) a[b] += h1[b][u] * w;
            }
            #pragma unroll
            for (int b = 0; b < BT; ++b) z[b][j] = a[b];
        }
        __syncthreads();

        // cell1 + BN1
        #pragma unroll
        for (int k2 = 0; k2 < 2; ++k2) {
            int k = tid + NTHREADS * k2;
            int b = k >> 7, u = k & 127;
            float ig = sigmoid_(z[b][u]);
            float fg = sigmoid_(z[b][u + UO]);
            float gg = selu_(z[b][u + 2 * UO]);
            float og = sigmoid_(z[b][u + 3 * UO]);
            float c = fg * c1[b][u] + ig * gg;
            float h = og * selu_(c);
            c1[b][u] = c; h1[b][u] = h;
            h1b[b][u] = h * s1[u] + t1[u];
        }
        __syncthreads();

        // z2[b][col] = b2[col] + h1b@Wk2 + h2@Wr2  (col per thread-pair, 4 b each)
        {
            const int col = tid & 255;
            const int bh = (tid >> 8) * 4;
            float bias = b2[col];
            float a[4];
            #pragma unroll
            for (int bb = 0; bb < 4; ++bb) a[bb] = bias;
            #pragma unroll 4
            for (int u = 0; u < UO; ++u) {
                float w = Wk2[u * G2 + col];
                #pragma unroll
                for (int bb = 0; bb < 4; ++bb) a[bb] += h1b[bh + bb][u] * w;
            }
            #pragma unroll 4
            for (int v_ = 0; v_ < UI; ++v_) {
                float w = Wr2[v_ * G2 + col];
                #pragma unroll
                for (int bb = 0; bb < 4; ++bb) a[bb] += h2[bh + bb][v_] * w;
            }
            #pragma unroll
            for (int bb = 0; bb < 4; ++bb) z[bh + bb][col] = a[bb];
        }
        __syncthreads();

        // cell2 (no per-step BN; BN2 applies to final enc only)
        {
            int b = tid >> 6, v_ = tid & 63;
            float ig = sigmoid_(z[b][v_]);
            float fg = sigmoid_(z[b][v_ + UI]);
            float gg = selu_(z[b][v_ + 2 * UI]);
            float og = sigmoid_(z[b][v_ + 3 * UI]);
            float c = fg * c2[b][v_] + ig * gg;
            float h = og * selu_(c);
            c2[b][v_] = c; h2[b][v_] = h;
        }
        __syncthreads();
    }

    // ===================== bottleneck =====================
    {
        int b = tid >> 6, v_ = tid & 63;
        encb[b][v_] = h2[b][v_] * s2[v_] + t2[v_];
    }
    __syncthreads();
    // xz3 = b3 + enc@Wk3 (constant across decoder steps: RepeatVector)
    {
        const int col = tid & 255;
        const int bh = (tid >> 8) * 4;
        float bias = b3[col];
        float a[4];
        #pragma unroll
        for (int bb = 0; bb < 4; ++bb) a[bb] = bias;
        #pragma unroll 4
        for (int v_ = 0; v_ < UI; ++v_) {
            float w = Wk3[v_ * G2 + col];
            #pragma unroll
            for (int bb = 0; bb < 4; ++bb) a[bb] += encb[bh + bb][v_] * w;
        }
        #pragma unroll
        for (int bb = 0; bb < 4; ++bb) xz3[bh + bb][col] = a[bb];
    }
    __syncthreads();

    // ===================== decoder =====================
    for (int t = 0; t < TT; ++t) {
        // z3[b][col] = xz3[b][col] + h3@Wr3
        {
            const int col = tid & 255;
            const int bh = (tid >> 8) * 4;
            float a[4];
            #pragma unroll
            for (int bb = 0; bb < 4; ++bb) a[bb] = xz3[bh + bb][col];
            #pragma unroll 4
            for (int v_ = 0; v_ < UI; ++v_) {
                float w = Wr3[v_ * G2 + col];
                #pragma unroll
                for (int bb = 0; bb < 4; ++bb) a[bb] += h3[bh + bb][v_] * w;
            }
            #pragma unroll
            for (int bb = 0; bb < 4; ++bb) z[bh + bb][col] = a[bb];
        }
        __syncthreads();

        // cell3 + BN3
        {
            int b = tid >> 6, v_ = tid & 63;
            float ig = sigmoid_(z[b][v_]);
            float fg = sigmoid_(z[b][v_ + UI]);
            float gg = selu_(z[b][v_ + 2 * UI]);
            float og = sigmoid_(z[b][v_ + 3 * UI]);
            float c = fg * c3[b][v_] + ig * gg;
            float h = og * selu_(c);
            c3[b][v_] = c; h3[b][v_] = h;
            h3b[b][v_] = h * s3[v_] + t3[v_];
        }
        __syncthreads();

        // z4[b][j] = b4[j] + h3b@Wk4 + h4@Wr4
        {
            const int j = tid;
            float bias = b4[j];
            float a[BT];
            #pragma unroll
            for (int b = 0; b < BT; ++b) a[b] = bias;
            #pragma unroll 4
            for (int v_ = 0; v_ < UI; ++v_) {
                float w = Wk4[v_ * G1 + j];
                #pragma unroll
                for (int b = 0; b < BT; ++b) a[b] += h3b[b][v_] * w;
            }
            #pragma unroll 4
            for (int u = 0; u < UO; ++u) {
                float w = Wr4[u * G1 + j];
                #pragma unroll
                for (int b = 0; b < BT; ++b) a[b] += h4[b][u] * w;
            }
            #pragma unroll
            for (int b = 0; b < BT; ++b) z[b][j] = a[b];
        }
        __syncthreads();

        // cell4 + BN4
        #pragma unroll
        for (int k2 = 0; k2 < 2; ++k2) {
            int k = tid + NTHREADS * k2;
            int b = k >> 7, u = k & 127;
            float ig = sigmoid_(z[b][u]);
            float fg = sigmoid_(z[b][u + UO]);
            float gg = selu_(z[b][u + 2 * UO]);
            float og = sigmoid_(z[b][u + 3 * UO]);
            float c = fg * c4[b][u] + ig * gg;
            float h = og * selu_(c);
            c4[b][u] = c; h4[b][u] = h;
            h4b[b][u] = h * s4[u] + t4[u];
        }
        __syncthreads();

        // dense heads: out[b][t][f] = bd[f] + h4b@Wd
        if (tid < BT * NF) {
            int b = tid >> 3, f = tid & 7;
            float a = bd[f];
            #pragma unroll 4
            for (int u = 0; u < UO; ++u) a += h4b[b][u] * Wd[u * NF + f];
            out[(size_t)(b0 + b) * TT * NF + (size_t)t * NF + f] = a;
        }
        __syncthreads();
    }
}

extern "C" void kernel_launch(void* const* d_in, const int* in_sizes, int n_in,
                              void* d_out, int out_size, void* d_ws, size_t ws_size,
                              hipStream_t stream) {
    const float* p[31];
    for (int i = 0; i < 31; ++i) p[i] = (const float*)d_in[i];
    lstm_ae_kernel<<<dim3(BATCH / BT), dim3(NTHREADS), 0, stream>>>(
        p[0],
        p[1], p[2], p[3], p[4], p[5], p[6], p[7],
        p[8], p[9], p[10], p[11], p[12], p[13], p[14],
        p[15], p[16], p[17], p[18], p[19], p[20], p[21],
        p[22], p[23], p[24], p[25], p[26], p[27], p[28],
        p[29], p[30],
        (float*)d_out);
}

// Round 2
// 2518.913 us; speedup vs baseline: 1.5880x; 1.5880x over previous
//
#include <hip/hip_runtime.h>
#include <math.h>

// LSTM autoencoder via MFMA (bf16 hi/lo error-compensated, ~f32 accuracy).
// 128 blocks x 512 threads (8 waves), BT=16 batch rows/block => M=16 exact.
// Weights pre-packed per launch into MFMA B-fragment order (hi/lo bf16) in
// d_ws; streamed from L2 each step. Hidden/cell state in LDS (ping-pong);
// gate accumulators + activations stay in registers (wave-strided N-tiles
// give each wave i,f,g,o for the same 16 columns).

typedef __attribute__((ext_vector_type(8))) short short8;
typedef __attribute__((ext_vector_type(4))) float floatx4;

#define TT 128
#define NF 8
#define UO 128
#define UI 64
#define BT 16
#define NBLK 128
#define NTH 512

// packed-fragment start indices (in 1024-ushort frag units)
#define FS_Z1 0     // K'=160 (Wr1 128 | Wk1 8 | pad), N=512 : 32 tiles x 5 ks
#define FS_Z2 160   // K'=192 (Wk2 128 | Wr2 64),     N=256 : 16 x 6
#define FS_X3 256   // K =64  (Wk3),                  N=256 : 16 x 2
#define FS_Z3 288   // K =64  (Wr3),                  N=256 : 16 x 2
#define FS_Z4 320   // K'=192 (Wk4 64 | Wr4 128),     N=512 : 32 x 6
#define FS_DN 512   // K =128 (Wd), N=16 (cols 8-15 zero) : 1 x 4
#define N_FRAGS 516

__device__ __forceinline__ unsigned short bf16hi(float x){
    unsigned u = __float_as_uint(x);
    u += 0x7fffu + ((u >> 16) & 1u);          // round-to-nearest-even
    return (unsigned short)(u >> 16);
}
__device__ __forceinline__ float bf16f(unsigned short h){
    return __uint_as_float(((unsigned)h) << 16);
}
__device__ __forceinline__ float sigmoid_(float x){ return 1.0f/(1.0f+__expf(-x)); }
__device__ __forceinline__ float selu_(float x){
    const float alpha = 1.6732632423543772f, scale = 1.0507009873554805f;
    return x > 0.0f ? scale*x : scale*alpha*(__expf(x)-1.0f);
}

struct ABfrag { short8 hi, lo; };

__device__ __forceinline__ ABfrag cvt8(const float* src){ // src 16B-aligned, 8 f32
    floatx4 a = *(const floatx4*)src;
    floatx4 b = *(const floatx4*)(src + 4);
    float v[8] = {a[0],a[1],a[2],a[3],b[0],b[1],b[2],b[3]};
    ABfrag r;
    #pragma unroll
    for (int j = 0; j < 8; ++j){
        unsigned short h = bf16hi(v[j]);
        unsigned short l = bf16hi(v[j] - bf16f(h));
        r.hi[j] = (short)h; r.lo[j] = (short)l;
    }
    return r;
}

__device__ __forceinline__ floatx4 mfma3(const ABfrag& a, const unsigned short* bp,
                                         int lane, floatx4 acc){
    short8 bh = *(const short8*)(bp + (size_t)lane * 8);
    short8 bl = *(const short8*)(bp + 512 + (size_t)lane * 8);
    acc = __builtin_amdgcn_mfma_f32_16x16x32_bf16(a.hi, bh, acc, 0, 0, 0);
    acc = __builtin_amdgcn_mfma_f32_16x16x32_bf16(a.lo, bh, acc, 0, 0, 0);
    acc = __builtin_amdgcn_mfma_f32_16x16x32_bf16(a.hi, bl, acc, 0, 0, 0);
    return acc;
}

// ---------------- pack kernel: weights -> B-fragment order, bf16 hi/lo ------
__global__ void pack_kernel(const float* __restrict__ Wk1, const float* __restrict__ Wr1,
                            const float* __restrict__ Wk2, const float* __restrict__ Wr2,
                            const float* __restrict__ Wk3, const float* __restrict__ Wr3,
                            const float* __restrict__ Wk4, const float* __restrict__ Wr4,
                            const float* __restrict__ Wd, unsigned short* __restrict__ ws)
{
    const int g = blockIdx.x;          // global frag index
    const int l = threadIdx.x;         // lane 0..63
    int blob, fs, KS;
    if      (g < FS_Z2){ blob = 0; fs = FS_Z1; KS = 5; }
    else if (g < FS_X3){ blob = 1; fs = FS_Z2; KS = 6; }
    else if (g < FS_Z3){ blob = 2; fs = FS_X3; KS = 2; }
    else if (g < FS_Z4){ blob = 3; fs = FS_Z3; KS = 2; }
    else if (g < FS_DN){ blob = 4; fs = FS_Z4; KS = 6; }
    else               { blob = 5; fs = FS_DN; KS = 4; }
    const int fl = g - fs;
    const int tile = fl / KS, kk = fl % KS;
    const int col = tile * 16 + (l & 15);
    const int k0  = kk * 32 + (l >> 4) * 8;

    short8 hi8, lo8;
    #pragma unroll
    for (int j = 0; j < 8; ++j){
        const int k = k0 + j;
        float v = 0.0f;
        switch (blob){
            case 0: v = (k < 128) ? Wr1[k*512 + col] : (k < 136 ? Wk1[(k-128)*512 + col] : 0.0f); break;
            case 1: v = (k < 128) ? Wk2[k*256 + col] : Wr2[(k-128)*256 + col]; break;
            case 2: v = Wk3[k*256 + col]; break;
            case 3: v = Wr3[k*256 + col]; break;
            case 4: v = (k < 64) ? Wk4[k*512 + col] : Wr4[(k-64)*512 + col]; break;
            case 5: v = (col < 8) ? Wd[k*8 + col] : 0.0f; break;
        }
        unsigned short h = bf16hi(v);
        unsigned short lo = bf16hi(v - bf16f(h));
        hi8[j] = (short)h; lo8[j] = (short)lo;
    }
    *(short8*)(ws + (size_t)g*1024 + l*8)       = hi8;
    *(short8*)(ws + (size_t)g*1024 + 512 + l*8) = lo8;
}

// ---------------- main kernel ------------------------------------------------
// LDS float offsets
#define OFF_H1  0        // [2][16][132]
#define OFF_H1B 4224     // [16][132]
#define OFF_C1  6336     // [16][128]
#define OFF_H2  8384     // [2][16][68]
#define OFF_C2  10560    // [16][64]
#define OFF_H3  11584    // [2][16][68]
#define OFF_H3B 13760    // [16][68]
#define OFF_C3  14848    // [16][64]
#define OFF_H4  15872    // [2][16][132]
#define OFF_H4B 20096    // [16][132]
#define OFF_C4  22208    // [16][128]
#define OFF_S1  24256
#define OFF_T1  24384
#define OFF_S2  24512
#define OFF_T2  24576
#define OFF_S3  24640
#define OFF_T3  24704
#define OFF_S4  24768
#define OFF_T4  24896
#define SM_FLOATS 25024

#define H1(p,m,k)  sm[OFF_H1 + (((p)*16+(m))*132) + (k)]
#define H1B(m,k)   sm[OFF_H1B + (m)*132 + (k)]
#define C1(m,u)    sm[OFF_C1 + (m)*128 + (u)]
#define H2(p,m,k)  sm[OFF_H2 + (((p)*16+(m))*68) + (k)]
#define C2(m,u)    sm[OFF_C2 + (m)*64 + (u)]
#define H3(p,m,k)  sm[OFF_H3 + (((p)*16+(m))*68) + (k)]
#define H3B(m,k)   sm[OFF_H3B + (m)*68 + (k)]
#define C3(m,u)    sm[OFF_C3 + (m)*64 + (u)]
#define H4(p,m,k)  sm[OFF_H4 + (((p)*16+(m))*132) + (k)]
#define H4B(m,k)   sm[OFF_H4B + (m)*132 + (k)]
#define C4(m,u)    sm[OFF_C4 + (m)*128 + (u)]

__global__ __launch_bounds__(NTH, 2) void lstm_ae_mfma(
    const float* __restrict__ x,
    const float* __restrict__ b1, const float* __restrict__ b2,
    const float* __restrict__ b3, const float* __restrict__ b4,
    const float* __restrict__ bd,
    const float* __restrict__ g1, const float* __restrict__ be1, const float* __restrict__ m1, const float* __restrict__ v1,
    const float* __restrict__ g2, const float* __restrict__ be2, const float* __restrict__ m2, const float* __restrict__ v2,
    const float* __restrict__ g3, const float* __restrict__ be3, const float* __restrict__ m3, const float* __restrict__ v3,
    const float* __restrict__ g4, const float* __restrict__ be4, const float* __restrict__ m4, const float* __restrict__ v4,
    const unsigned short* __restrict__ WS,
    float* __restrict__ out)
{
    __shared__ __align__(16) float sm[SM_FLOATS];

    const int tid = threadIdx.x;
    const int w = tid >> 6;            // wave 0..7
    const int l = tid & 63;
    const int lane15 = l & 15, q = l >> 4;
    const int b0 = blockIdx.x * BT;

    const unsigned short* bZ1 = WS + (size_t)FS_Z1 * 1024;
    const unsigned short* bZ2 = WS + (size_t)FS_Z2 * 1024;
    const unsigned short* bX3 = WS + (size_t)FS_X3 * 1024;
    const unsigned short* bZ3 = WS + (size_t)FS_Z3 * 1024;
    const unsigned short* bZ4 = WS + (size_t)FS_Z4 * 1024;
    const unsigned short* bDN = WS + (size_t)FS_DN * 1024;

    for (int i = tid; i < SM_FLOATS; i += NTH) sm[i] = 0.0f;
    __syncthreads();
    if (tid < UO){
        float s  = g1[tid]*rsqrtf(v1[tid]+1e-3f); sm[OFF_S1+tid]=s;  sm[OFF_T1+tid]=be1[tid]-m1[tid]*s;
        float s4 = g4[tid]*rsqrtf(v4[tid]+1e-3f); sm[OFF_S4+tid]=s4; sm[OFF_T4+tid]=be4[tid]-m4[tid]*s4;
    } else if (tid < UO + UI){
        int u = tid - UO;
        float s2 = g2[u]*rsqrtf(v2[u]+1e-3f); sm[OFF_S2+u]=s2; sm[OFF_T2+u]=be2[u]-m2[u]*s2;
        float s3 = g3[u]*rsqrtf(v3[u]+1e-3f); sm[OFF_S3+u]=s3; sm[OFF_T3+u]=be3[u]-m3[u]*s3;
    }
    float z1b[4], z4b[4], z2b[4], b3v[4];
    #pragma unroll
    for (int i = 0; i < 4; ++i){
        z1b[i] = b1[(w + 8*i)*16 + lane15];
        z4b[i] = b4[(w + 8*i)*16 + lane15];
    }
    if (w < 4){
        #pragma unroll
        for (int i = 0; i < 4; ++i){
            z2b[i] = b2[(w + 4*i)*16 + lane15];
            b3v[i] = b3[(w + 4*i)*16 + lane15];
        }
    }
    const float bdv = (w == 0 && lane15 < 8) ? bd[lane15] : 0.0f;
    __syncthreads();

    // ===================== encoder =====================
    int ping = 0;
    for (int t = 0; t < TT; ++t){
        floatx4 acc[4];
        #pragma unroll
        for (int i = 0; i < 4; ++i) acc[i] = (floatx4){z1b[i], z1b[i], z1b[i], z1b[i]};
        #pragma unroll
        for (int kk = 0; kk < 5; ++kk){
            ABfrag a;
            if (kk < 4){
                a = cvt8(&H1(ping, lane15, kk*32 + q*8));
            } else if (q == 0){
                a = cvt8(x + (size_t)(b0 + lane15)*(TT*NF) + (size_t)t*NF);
            } else {
                a.hi = (short8){0,0,0,0,0,0,0,0}; a.lo = a.hi;
            }
            #pragma unroll
            for (int i = 0; i < 4; ++i)
                acc[i] = mfma3(a, bZ1 + (size_t)((w + 8*i)*5 + kk)*1024, l, acc[i]);
        }
        {   // cell1 + BN1 (in registers)
            const int u = w*16 + lane15;
            const float sv = sm[OFF_S1+u], tv = sm[OFF_T1+u];
            #pragma unroll
            for (int r = 0; r < 4; ++r){
                const int row = q*4 + r;
                float ig = sigmoid_(acc[0][r]);
                float fg = sigmoid_(acc[1][r]);
                float gg = selu_(acc[2][r]);
                float og = sigmoid_(acc[3][r]);
                float c = fg * C1(row,u) + ig*gg;
                float h = og * selu_(c);
                C1(row,u) = c;
                H1(ping^1,row,u) = h;
                H1B(row,u) = h*sv + tv;
            }
        }
        __syncthreads();
        if (w < 4){
            floatx4 acc2[4];
            #pragma unroll
            for (int i = 0; i < 4; ++i) acc2[i] = (floatx4){z2b[i], z2b[i], z2b[i], z2b[i]};
            #pragma unroll
            for (int kk = 0; kk < 6; ++kk){
                ABfrag a = (kk < 4) ? cvt8(&H1B(lane15, kk*32 + q*8))
                                    : cvt8(&H2(ping, lane15, (kk-4)*32 + q*8));
                #pragma unroll
                for (int i = 0; i < 4; ++i)
                    acc2[i] = mfma3(a, bZ2 + (size_t)((w + 4*i)*6 + kk)*1024, l, acc2[i]);
            }
            const int u = w*16 + lane15;
            #pragma unroll
            for (int r = 0; r < 4; ++r){
                const int row = q*4 + r;
                float ig = sigmoid_(acc2[0][r]);
                float fg = sigmoid_(acc2[1][r]);
                float gg = selu_(acc2[2][r]);
                float og = sigmoid_(acc2[3][r]);
                float c = fg * C2(row,u) + ig*gg;
                float h = og * selu_(c);
                C2(row,u) = c;
                H2(ping^1,row,u) = h;           // BN2 applies only to final enc
            }
        }
        __syncthreads();
        ping ^= 1;
    }

    // ===================== bottleneck =====================
    for (int i2 = tid; i2 < BT*UI; i2 += NTH){   // encb -> h3b (A-layout buffer)
        int row = i2 >> 6, u = i2 & 63;
        H3B(row,u) = H2(ping,row,u)*sm[OFF_S2+u] + sm[OFF_T2+u];
    }
    __syncthreads();
    floatx4 xz3a[4];
    if (w < 4){
        #pragma unroll
        for (int i = 0; i < 4; ++i) xz3a[i] = (floatx4){b3v[i], b3v[i], b3v[i], b3v[i]};
        #pragma unroll
        for (int kk = 0; kk < 2; ++kk){
            ABfrag a = cvt8(&H3B(lane15, kk*32 + q*8));
            #pragma unroll
            for (int i = 0; i < 4; ++i)
                xz3a[i] = mfma3(a, bX3 + (size_t)((w + 4*i)*2 + kk)*1024, l, xz3a[i]);
        }
    }
    __syncthreads();

    // ===================== decoder =====================
    ping = 0;
    for (int t = 0; t < TT; ++t){
        if (w < 4){
            floatx4 acc3[4];
            #pragma unroll
            for (int i = 0; i < 4; ++i) acc3[i] = xz3a[i];
            #pragma unroll
            for (int kk = 0; kk < 2; ++kk){
                ABfrag a = cvt8(&H3(ping, lane15, kk*32 + q*8));
                #pragma unroll
                for (int i = 0; i < 4; ++i)
                    acc3[i] = mfma3(a, bZ3 + (size_t)((w + 4*i)*2 + kk)*1024, l, acc3[i]);
            }
            const int u = w*16 + lane15;
            const float sv = sm[OFF_S3+u], tv = sm[OFF_T3+u];
            #pragma unroll
            for (int r = 0; r < 4; ++r){
                const int row = q*4 + r;
                float ig = sigmoid_(acc3[0][r]);
                float fg = sigmoid_(acc3[1][r]);
                float gg = selu_(acc3[2][r]);
                float og = sigmoid_(acc3[3][r]);
                float c = fg * C3(row,u) + ig*gg;
                float h = og * selu_(c);
                C3(row,u) = c;
                H3(ping^1,row,u) = h;
                H3B(row,u) = h*sv + tv;
            }
        }
        __syncthreads();
        {
            floatx4 acc4[4];
            #pragma unroll
            for (int i = 0; i < 4; ++i) acc4[i] = (floatx4){z4b[i], z4b[i], z4b[i], z4b[i]};
            #pragma unroll
            for (int kk = 0; kk < 6; ++kk){
                ABfrag a = (kk < 2) ? cvt8(&H3B(lane15, kk*32 + q*8))
                                    : cvt8(&H4(ping, lane15, (kk-2)*32 + q*8));
                #pragma unroll
                for (int i = 0; i < 4; ++i)
                    acc4[i] = mfma3(a, bZ4 + (size_t)((w + 8*i)*6 + kk)*1024, l, acc4[i]);
            }
            const int u = w*16 + lane15;
            const float sv = sm[OFF_S4+u], tv = sm[OFF_T4+u];
            #pragma unroll
            for (int r = 0; r < 4; ++r){
                const int row = q*4 + r;
                float ig = sigmoid_(acc4[0][r]);
                float fg = sigmoid_(acc4[1][r]);
                float gg = selu_(acc4[2][r]);
                float og = sigmoid_(acc4[3][r]);
                float c = fg * C4(row,u) + ig*gg;
                float h = og * selu_(c);
                C4(row,u) = c;
                H4(ping^1,row,u) = h;
                H4B(row,u) = h*sv + tv;
            }
        }
        __syncthreads();
        if (w == 0){   // dense heads via MFMA (N padded 8->16)
            floatx4 ad = (floatx4){bdv, bdv, bdv, bdv};
            #pragma unroll
            for (int kk = 0; kk < 4; ++kk){
                ABfrag a = cvt8(&H4B(lane15, kk*32 + q*8));
                ad = mfma3(a, bDN + (size_t)kk*1024, l, ad);
            }
            if (lane15 < 8){
                #pragma unroll
                for (int r = 0; r < 4; ++r){
                    const int row = q*4 + r;
                    out[(size_t)(b0 + row)*(TT*NF) + (size_t)t*NF + lane15] = ad[r];
                }
            }
        }
        ping ^= 1;
    }
}

extern "C" void kernel_launch(void* const* d_in, const int* in_sizes, int n_in,
                              void* d_out, int out_size, void* d_ws, size_t ws_size,
                              hipStream_t stream) {
    const float* x   = (const float*)d_in[0];
    const float* Wk1 = (const float*)d_in[1];  const float* Wr1 = (const float*)d_in[2];
    const float* b1  = (const float*)d_in[3];
    const float* g1  = (const float*)d_in[4];  const float* be1 = (const float*)d_in[5];
    const float* m1  = (const float*)d_in[6];  const float* v1  = (const float*)d_in[7];
    const float* Wk2 = (const float*)d_in[8];  const float* Wr2 = (const float*)d_in[9];
    const float* b2  = (const float*)d_in[10];
    const float* g2  = (const float*)d_in[11]; const float* be2 = (const float*)d_in[12];
    const float* m2  = (const float*)d_in[13]; const float* v2  = (const float*)d_in[14];
    const float* Wk3 = (const float*)d_in[15]; const float* Wr3 = (const float*)d_in[16];
    const float* b3  = (const float*)d_in[17];
    const float* g3  = (const float*)d_in[18]; const float* be3 = (const float*)d_in[19];
    const float* m3  = (const float*)d_in[20]; const float* v3  = (const float*)d_in[21];
    const float* Wk4 = (const float*)d_in[22]; const float* Wr4 = (const float*)d_in[23];
    const float* b4  = (const float*)d_in[24];
    const float* g4  = (const float*)d_in[25]; const float* be4 = (const float*)d_in[26];
    const float* m4  = (const float*)d_in[27]; const float* v4  = (const float*)d_in[28];
    const float* Wd  = (const float*)d_in[29]; const float* bd  = (const float*)d_in[30];

    unsigned short* ws = (unsigned short*)d_ws;

    pack_kernel<<<dim3(N_FRAGS), dim3(64), 0, stream>>>(Wk1, Wr1, Wk2, Wr2, Wk3, Wr3,
                                                        Wk4, Wr4, Wd, ws);
    lstm_ae_mfma<<<dim3(NBLK), dim3(NTH), 0, stream>>>(
        x, b1, b2, b3, b4, bd,
        g1, be1, m1, v1, g2, be2, m2, v2,
        g3, be3, m3, v3, g4, be4, m4, v4,
        (const unsigned short*)ws, (float*)d_out);
}

// Round 3
// 859.639 us; speedup vs baseline: 4.6533x; 2.9302x over previous
//
#include <hip/hip_runtime.h>
#include <math.h>

// LSTM autoencoder, MFMA with register-stationary bf16 weights.
// 128 blocks x 512 threads (8 waves), BT=16 rows/block.
// - Weights packed once (pack_kernel) into B-fragment order; each wave loads
//   its fragments into VGPRs once per phase (encoder / decoder) -> no per-step
//   weight streaming.
// - Hidden state kept in LDS as bf16 hi/lo planes laid out in MFMA A-fragment
//   order; f32->bf16x2 conversion happens once at cell-write time, A-reads are
//   bare ds_read_b128.
// - A = hi+lo (error-compensated), B = bf16 hi only => 2 MFMA per tile-kk.
// - z1/z4 cells fully register-resident (wave-strided N-tiles give each lane
//   i,f,g,o for one u). z2/z3 balanced over all 8 waves via LDS z-scratch
//   (row stride 260 to break bank conflicts). c-state in registers.

typedef __attribute__((ext_vector_type(8))) short short8;
typedef __attribute__((ext_vector_type(4))) float floatx4;

#define TT 128
#define NF 8
#define BT 16
#define NBLK 128
#define NTH 512

// packed-fragment start indices (in 1024-ushort frag units); hi at +0, lo at +512
#define FS_Z1 0     // K'=160 (Wr1 128 | Wk1 8 | pad), N=512 : 32 tiles x 5 ks
#define FS_Z2 160   // K'=192 (Wk2 128 | Wr2 64),     N=256 : 16 x 6
#define FS_X3 256   // K =64  (Wk3),                  N=256 : 16 x 2
#define FS_Z3 288   // K =64  (Wr3),                  N=256 : 16 x 2
#define FS_Z4 320   // K'=192 (Wk4 64 | Wr4 128),     N=512 : 32 x 6
#define FS_DN 512   // K =128 (Wd), N=16 (cols 8-15 zero) : 1 x 4
#define N_FRAGS 516

#define MFMA(a,b,c) __builtin_amdgcn_mfma_f32_16x16x32_bf16((a),(b),(c),0,0,0)

__device__ __forceinline__ unsigned short bf16hi(float x){
    unsigned u = __float_as_uint(x);
    u += 0x7fffu + ((u >> 16) & 1u);
    return (unsigned short)(u >> 16);
}
__device__ __forceinline__ float bf16f(unsigned short h){
    return __uint_as_float(((unsigned)h) << 16);
}
__device__ __forceinline__ float sigmoid_(float x){ return 1.0f/(1.0f+__expf(-x)); }
__device__ __forceinline__ float selu_(float x){
    const float alpha = 1.6732632423543772f, scale = 1.0507009873554805f;
    return x > 0.0f ? scale*x : scale*alpha*(__expf(x)-1.0f);
}

// ---------------- pack kernel: weights -> B-fragment order, bf16 hi/lo ------
__global__ void pack_kernel(const float* __restrict__ Wk1, const float* __restrict__ Wr1,
                            const float* __restrict__ Wk2, const float* __restrict__ Wr2,
                            const float* __restrict__ Wk3, const float* __restrict__ Wr3,
                            const float* __restrict__ Wk4, const float* __restrict__ Wr4,
                            const float* __restrict__ Wd, unsigned short* __restrict__ ws)
{
    const int g = blockIdx.x;
    const int l = threadIdx.x;
    int blob, fs, KS;
    if      (g < FS_Z2){ blob = 0; fs = FS_Z1; KS = 5; }
    else if (g < FS_X3){ blob = 1; fs = FS_Z2; KS = 6; }
    else if (g < FS_Z3){ blob = 2; fs = FS_X3; KS = 2; }
    else if (g < FS_Z4){ blob = 3; fs = FS_Z3; KS = 2; }
    else if (g < FS_DN){ blob = 4; fs = FS_Z4; KS = 6; }
    else               { blob = 5; fs = FS_DN; KS = 4; }
    const int fl = g - fs;
    const int tile = fl / KS, kk = fl % KS;
    const int col = tile * 16 + (l & 15);
    const int k0  = kk * 32 + (l >> 4) * 8;

    short8 hi8, lo8;
    #pragma unroll
    for (int j = 0; j < 8; ++j){
        const int k = k0 + j;
        float v = 0.0f;
        switch (blob){
            case 0: v = (k < 128) ? Wr1[k*512 + col] : (k < 136 ? Wk1[(k-128)*512 + col] : 0.0f); break;
            case 1: v = (k < 128) ? Wk2[k*256 + col] : Wr2[(k-128)*256 + col]; break;
            case 2: v = Wk3[k*256 + col]; break;
            case 3: v = Wr3[k*256 + col]; break;
            case 4: v = (k < 64) ? Wk4[k*512 + col] : Wr4[(k-64)*512 + col]; break;
            case 5: v = (col < 8) ? Wd[k*8 + col] : 0.0f; break;
        }
        unsigned short h = bf16hi(v);
        unsigned short lo = bf16hi(v - bf16f(h));
        hi8[j] = (short)h; lo8[j] = (short)lo;
    }
    *(short8*)(ws + (size_t)g*1024 + l*8)       = hi8;
    *(short8*)(ws + (size_t)g*1024 + 512 + l*8) = lo8;
}

// ---------------- main kernel ------------------------------------------------
__global__ __launch_bounds__(NTH, 2) void lstm_ae_mfma(
    const float* __restrict__ x,
    const float* __restrict__ b1, const float* __restrict__ b2,
    const float* __restrict__ b3, const float* __restrict__ b4,
    const float* __restrict__ bd,
    const float* __restrict__ g1, const float* __restrict__ be1, const float* __restrict__ m1, const float* __restrict__ v1,
    const float* __restrict__ g2, const float* __restrict__ be2, const float* __restrict__ m2, const float* __restrict__ v2,
    const float* __restrict__ g3, const float* __restrict__ be3, const float* __restrict__ m3, const float* __restrict__ v3,
    const float* __restrict__ g4, const float* __restrict__ be4, const float* __restrict__ m4, const float* __restrict__ v4,
    const unsigned short* __restrict__ WS,
    float* __restrict__ out)
{
    // A-fragment planes: [hi/lo][kk][lane*8 + j], lane = (kq<<4)|m
    __shared__ __align__(16) short AZ1[2][2][5][512];   // ping x h/l; kk4 = x (q=0) + zero pad
    __shared__ __align__(16) short AH1B[2][4][512];
    __shared__ __align__(16) short AH2[2][2][2][512];
    __shared__ __align__(16) short AH3[2][2][2][512];
    __shared__ __align__(16) short AH3B[2][2][512];
    __shared__ __align__(16) short AH4[2][2][4][512];
    __shared__ __align__(16) short AH4B[2][4][512];
    __shared__ __align__(16) float ZSC[16*260];         // z2/z3 scratch, padded stride

    const int tid = threadIdx.x;
    const int w = tid >> 6, l = tid & 63;
    const int l15 = l & 15, q = l >> 4;
    const int b0 = blockIdx.x * BT;

    // ---- per-lane constants ----
    const int u1 = 16*w + l15;                          // z1/z4 cell column
    const float s1v = g1[u1]*rsqrtf(v1[u1]+1e-3f), t1v = be1[u1]-m1[u1]*s1v;
    const float s4v = g4[u1]*rsqrtf(v4[u1]+1e-3f), t4v = be4[u1]-m4[u1]*s4v;
    const int kk1 = u1 >> 5;
    const int sbase1 = ((u1>>3)&3)*128 + (u1&7);        // + row*8

    const int c2row = l15;                              // cell2/cell3 mapping
    int   u2k[2], kk2[2], s2i[2];
    float s2r[2], t2r[2], s3r[2], t3r[2];
    #pragma unroll
    for (int k2 = 0; k2 < 2; ++k2){
        const int u = (l>>4) + 4*w + 32*k2;             // 0..63, unique per (thread,k2)
        u2k[k2] = u;
        kk2[k2] = u >> 5;
        s2i[k2] = (((u>>3)&3)*16 + c2row)*8 + (u&7);
        float s2 = g2[u]*rsqrtf(v2[u]+1e-3f); s2r[k2]=s2; t2r[k2]=be2[u]-m2[u]*s2;
        float s3 = g3[u]*rsqrtf(v3[u]+1e-3f); s3r[k2]=s3; t3r[k2]=be3[u]-m3[u]*s3;
    }

    float z1b[4], z4b[4], z2b[2], b3v[2];
    #pragma unroll
    for (int i = 0; i < 4; ++i){
        z1b[i] = b1[(w + 8*i)*16 + l15];
        z4b[i] = b4[(w + 8*i)*16 + l15];
    }
    #pragma unroll
    for (int i = 0; i < 2; ++i){
        z2b[i] = b2[32*w + 16*i + l15];
        b3v[i] = b3[32*w + 16*i + l15];
    }
    const float bdv = (w == 0 && l15 < 8) ? bd[l15] : 0.0f;

    // ---- stationary encoder weights (hi halves) ----
    short8 wz1[4][5], wz2[2][6];
    #pragma unroll
    for (int i = 0; i < 4; ++i)
        #pragma unroll
        for (int kk = 0; kk < 5; ++kk)
            wz1[i][kk] = *(const short8*)(WS + (size_t)(FS_Z1 + (w+8*i)*5 + kk)*1024 + l*8);
    #pragma unroll
    for (int i = 0; i < 2; ++i)
        #pragma unroll
        for (int kk = 0; kk < 6; ++kk)
            wz2[i][kk] = *(const short8*)(WS + (size_t)(FS_Z2 + (2*w+i)*6 + kk)*1024 + l*8);

    // ---- prologue: zero t=0 state planes, stage x[0] ----
    for (int i = tid; i < 5120; i += NTH) ((int*)AZ1)[i] = 0;          // all of AZ1
    for (int i = tid; i < 1024; i += NTH){ ((int*)AH2[0])[i] = 0; ((int*)AH3[0])[i] = 0; }
    for (int i = tid; i < 2048; i += NTH) ((int*)AH4[0])[i] = 0;
    if (tid < 128){
        int row = tid >> 3, j = tid & 7;
        float xv = x[(size_t)(b0+row)*(TT*NF) + j];
        unsigned short xh = bf16hi(xv);
        AZ1[0][0][4][row*8+j] = (short)xh;
        AZ1[0][1][4][row*8+j] = (short)bf16hi(xv - bf16f(xh));
    }
    float c1r[4] = {0,0,0,0}, c4r[4] = {0,0,0,0};
    float c2r[2] = {0,0}, c3r[2] = {0,0};
    __syncthreads();

    // ===================== encoder =====================
    int p = 0;
    for (int t = 0; t < TT; ++t){
        // --- z1 (all waves, 4 tiles each) ---
        floatx4 acc[4];
        #pragma unroll
        for (int i = 0; i < 4; ++i) acc[i] = (floatx4){z1b[i],z1b[i],z1b[i],z1b[i]};
        #pragma unroll
        for (int kk = 0; kk < 5; ++kk){
            short8 ah = *(const short8*)&AZ1[p][0][kk][l*8];
            short8 al = *(const short8*)&AZ1[p][1][kk][l*8];
            #pragma unroll
            for (int i = 0; i < 4; ++i){
                acc[i] = MFMA(ah, wz1[i][kk], acc[i]);
                acc[i] = MFMA(al, wz1[i][kk], acc[i]);
            }
        }
        // --- cell1 + BN1, register-resident ---
        #pragma unroll
        for (int r = 0; r < 4; ++r){
            const int row = q*4 + r;
            float ig = sigmoid_(acc[0][r]);
            float fg = sigmoid_(acc[1][r]);
            float gg = selu_(acc[2][r]);
            float og = sigmoid_(acc[3][r]);
            float c = fg*c1r[r] + ig*gg; c1r[r] = c;
            float h = og*selu_(c);
            float hb = h*s1v + t1v;
            const int s = sbase1 + row*8;
            unsigned short hh = bf16hi(h);
            AZ1[p^1][0][kk1][s] = (short)hh;
            AZ1[p^1][1][kk1][s] = (short)bf16hi(h - bf16f(hh));
            unsigned short bh_ = bf16hi(hb);
            AH1B[0][kk1][s] = (short)bh_;
            AH1B[1][kk1][s] = (short)bf16hi(hb - bf16f(bh_));
        }
        // stage x[t+1] into the other ping
        if (tid < 128 && t+1 < TT){
            int row = tid >> 3, j = tid & 7;
            float xv = x[(size_t)(b0+row)*(TT*NF) + (size_t)(t+1)*NF + j];
            unsigned short xh = bf16hi(xv);
            AZ1[p^1][0][4][row*8+j] = (short)xh;
            AZ1[p^1][1][4][row*8+j] = (short)bf16hi(xv - bf16f(xh));
        }
        __syncthreads();

        // --- z2 (all waves, 2 tiles each) -> scratch ---
        floatx4 a2[2];
        #pragma unroll
        for (int i = 0; i < 2; ++i) a2[i] = (floatx4){z2b[i],z2b[i],z2b[i],z2b[i]};
        #pragma unroll
        for (int kk = 0; kk < 6; ++kk){
            short8 ah, al;
            if (kk < 4){ ah = *(const short8*)&AH1B[0][kk][l*8];   al = *(const short8*)&AH1B[1][kk][l*8]; }
            else       { ah = *(const short8*)&AH2[p][0][kk-4][l*8]; al = *(const short8*)&AH2[p][1][kk-4][l*8]; }
            #pragma unroll
            for (int i = 0; i < 2; ++i){
                a2[i] = MFMA(ah, wz2[i][kk], a2[i]);
                a2[i] = MFMA(al, wz2[i][kk], a2[i]);
            }
        }
        #pragma unroll
        for (int i = 0; i < 2; ++i)
            #pragma unroll
            for (int r = 0; r < 4; ++r)
                ZSC[(q*4+r)*260 + 32*w + 16*i + l15] = a2[i][r];
        __syncthreads();

        // --- cell2 (scratch -> registers -> AH2 planes) ---
        #pragma unroll
        for (int k2 = 0; k2 < 2; ++k2){
            const int u = u2k[k2];
            const float* zr = &ZSC[c2row*260];
            float ig = sigmoid_(zr[u]);
            float fg = sigmoid_(zr[64+u]);
            float gg = selu_(zr[128+u]);
            float og = sigmoid_(zr[192+u]);
            float c = fg*c2r[k2] + ig*gg; c2r[k2] = c;
            float h = og*selu_(c);
            unsigned short hh = bf16hi(h);
            AH2[p^1][0][kk2[k2]][s2i[k2]] = (short)hh;
            AH2[p^1][1][kk2[k2]][s2i[k2]] = (short)bf16hi(h - bf16f(hh));
        }
        __syncthreads();
        p ^= 1;
    }

    // ===================== bottleneck =====================
    // encb = BN2(h2_final) -> AH3B planes
    #pragma unroll
    for (int k2 = 0; k2 < 2; ++k2){
        float h2v = bf16f((unsigned short)AH2[p][0][kk2[k2]][s2i[k2]])
                  + bf16f((unsigned short)AH2[p][1][kk2[k2]][s2i[k2]]);
        float e = h2v*s2r[k2] + t2r[k2];
        unsigned short eh = bf16hi(e);
        AH3B[0][kk2[k2]][s2i[k2]] = (short)eh;
        AH3B[1][kk2[k2]][s2i[k2]] = (short)bf16hi(e - bf16f(eh));
    }
    __syncthreads();
    // xz3 = b3 + enc@Wk3, persistent in registers (streamed hi/lo B, one-time)
    floatx4 xz3r[2];
    #pragma unroll
    for (int i = 0; i < 2; ++i) xz3r[i] = (floatx4){b3v[i],b3v[i],b3v[i],b3v[i]};
    #pragma unroll
    for (int kk = 0; kk < 2; ++kk){
        short8 ah = *(const short8*)&AH3B[0][kk][l*8];
        short8 al = *(const short8*)&AH3B[1][kk][l*8];
        #pragma unroll
        for (int i = 0; i < 2; ++i){
            const unsigned short* bp = WS + (size_t)(FS_X3 + (2*w+i)*2 + kk)*1024;
            short8 bh = *(const short8*)(bp + l*8);
            short8 bl = *(const short8*)(bp + 512 + l*8);
            xz3r[i] = MFMA(ah, bh, xz3r[i]);
            xz3r[i] = MFMA(al, bh, xz3r[i]);
            xz3r[i] = MFMA(ah, bl, xz3r[i]);
        }
    }
    // ---- stationary decoder weights ----
    short8 wz3[2][2], wz4[4][6], wdn[4];
    #pragma unroll
    for (int i = 0; i < 2; ++i)
        #pragma unroll
        for (int kk = 0; kk < 2; ++kk)
            wz3[i][kk] = *(const short8*)(WS + (size_t)(FS_Z3 + (2*w+i)*2 + kk)*1024 + l*8);
    #pragma unroll
    for (int i = 0; i < 4; ++i)
        #pragma unroll
        for (int kk = 0; kk < 6; ++kk)
            wz4[i][kk] = *(const short8*)(WS + (size_t)(FS_Z4 + (w+8*i)*6 + kk)*1024 + l*8);
    if (w == 0){
        #pragma unroll
        for (int kk = 0; kk < 4; ++kk)
            wdn[kk] = *(const short8*)(WS + (size_t)(FS_DN + kk)*1024 + l*8);
    }

    // ===================== decoder =====================
    p = 0;
    for (int t = 0; t < TT; ++t){
        // --- slot 1: dense(t-1) on wave0; z3 on all waves ---
        if (w == 0 && t > 0){
            floatx4 ad = (floatx4){bdv,bdv,bdv,bdv};
            #pragma unroll
            for (int kk = 0; kk < 4; ++kk){
                short8 ah = *(const short8*)&AH4B[0][kk][l*8];
                short8 al = *(const short8*)&AH4B[1][kk][l*8];
                ad = MFMA(ah, wdn[kk], ad);
                ad = MFMA(al, wdn[kk], ad);
            }
            if (l15 < 8){
                #pragma unroll
                for (int r = 0; r < 4; ++r)
                    out[(size_t)(b0 + q*4 + r)*(TT*NF) + (size_t)(t-1)*NF + l15] = ad[r];
            }
        }
        floatx4 a3[2];
        #pragma unroll
        for (int i = 0; i < 2; ++i) a3[i] = xz3r[i];
        #pragma unroll
        for (int kk = 0; kk < 2; ++kk){
            short8 ah = *(const short8*)&AH3[p][0][kk][l*8];
            short8 al = *(const short8*)&AH3[p][1][kk][l*8];
            #pragma unroll
            for (int i = 0; i < 2; ++i){
                a3[i] = MFMA(ah, wz3[i][kk], a3[i]);
                a3[i] = MFMA(al, wz3[i][kk], a3[i]);
            }
        }
        #pragma unroll
        for (int i = 0; i < 2; ++i)
            #pragma unroll
            for (int r = 0; r < 4; ++r)
                ZSC[(q*4+r)*260 + 32*w + 16*i + l15] = a3[i][r];
        __syncthreads();

        // --- cell3 + BN3 ---
        #pragma unroll
        for (int k2 = 0; k2 < 2; ++k2){
            const int u = u2k[k2];
            const float* zr = &ZSC[c2row*260];
            float ig = sigmoid_(zr[u]);
            float fg = sigmoid_(zr[64+u]);
            float gg = selu_(zr[128+u]);
            float og = sigmoid_(zr[192+u]);
            float c = fg*c3r[k2] + ig*gg; c3r[k2] = c;
            float h = og*selu_(c);
            float hb = h*s3r[k2] + t3r[k2];
            unsigned short hh = bf16hi(h);
            AH3[p^1][0][kk2[k2]][s2i[k2]] = (short)hh;
            AH3[p^1][1][kk2[k2]][s2i[k2]] = (short)bf16hi(h - bf16f(hh));
            unsigned short bh_ = bf16hi(hb);
            AH3B[0][kk2[k2]][s2i[k2]] = (short)bh_;
            AH3B[1][kk2[k2]][s2i[k2]] = (short)bf16hi(hb - bf16f(bh_));
        }
        __syncthreads();

        // --- z4 + cell4 + BN4 (register-resident) ---
        floatx4 a4[4];
        #pragma unroll
        for (int i = 0; i < 4; ++i) a4[i] = (floatx4){z4b[i],z4b[i],z4b[i],z4b[i]};
        #pragma unroll
        for (int kk = 0; kk < 6; ++kk){
            short8 ah, al;
            if (kk < 2){ ah = *(const short8*)&AH3B[0][kk][l*8];     al = *(const short8*)&AH3B[1][kk][l*8]; }
            else       { ah = *(const short8*)&AH4[p][0][kk-2][l*8]; al = *(const short8*)&AH4[p][1][kk-2][l*8]; }
            #pragma unroll
            for (int i = 0; i < 4; ++i){
                a4[i] = MFMA(ah, wz4[i][kk], a4[i]);
                a4[i] = MFMA(al, wz4[i][kk], a4[i]);
            }
        }
        #pragma unroll
        for (int r = 0; r < 4; ++r){
            const int row = q*4 + r;
            float ig = sigmoid_(a4[0][r]);
            float fg = sigmoid_(a4[1][r]);
            float gg = selu_(a4[2][r]);
            float og = sigmoid_(a4[3][r]);
            float c = fg*c4r[r] + ig*gg; c4r[r] = c;
            float h = og*selu_(c);
            float hb = h*s4v + t4v;
            const int s = sbase1 + row*8;
            unsigned short hh = bf16hi(h);
            AH4[p^1][0][kk1][s] = (short)hh;
            AH4[p^1][1][kk1][s] = (short)bf16hi(h - bf16f(hh));
            unsigned short bh_ = bf16hi(hb);
            AH4B[0][kk1][s] = (short)bh_;
            AH4B[1][kk1][s] = (short)bf16hi(hb - bf16f(bh_));
        }
        __syncthreads();
        p ^= 1;
    }

    // epilogue: dense for t = TT-1
    if (w == 0){
        floatx4 ad = (floatx4){bdv,bdv,bdv,bdv};
        #pragma unroll
        for (int kk = 0; kk < 4; ++kk){
            short8 ah = *(const short8*)&AH4B[0][kk][l*8];
            short8 al = *(const short8*)&AH4B[1][kk][l*8];
            ad = MFMA(ah, wdn[kk], ad);
            ad = MFMA(al, wdn[kk], ad);
        }
        if (l15 < 8){
            #pragma unroll
            for (int r = 0; r < 4; ++r)
                out[(size_t)(b0 + q*4 + r)*(TT*NF) + (size_t)(TT-1)*NF + l15] = ad[r];
        }
    }
}

extern "C" void kernel_launch(void* const* d_in, const int* in_sizes, int n_in,
                              void* d_out, int out_size, void* d_ws, size_t ws_size,
                              hipStream_t stream) {
    const float* x   = (const float*)d_in[0];
    const float* Wk1 = (const float*)d_in[1];  const float* Wr1 = (const float*)d_in[2];
    const float* b1  = (const float*)d_in[3];
    const float* g1  = (const float*)d_in[4];  const float* be1 = (const float*)d_in[5];
    const float* m1  = (const float*)d_in[6];  const float* v1  = (const float*)d_in[7];
    const float* Wk2 = (const float*)d_in[8];  const float* Wr2 = (const float*)d_in[9];
    const float* b2  = (const float*)d_in[10];
    const float* g2  = (const float*)d_in[11]; const float* be2 = (const float*)d_in[12];
    const float* m2  = (const float*)d_in[13]; const float* v2  = (const float*)d_in[14];
    const float* Wk3 = (const float*)d_in[15]; const float* Wr3 = (const float*)d_in[16];
    const float* b3  = (const float*)d_in[17];
    const float* g3  = (const float*)d_in[18]; const float* be3 = (const float*)d_in[19];
    const float* m3  = (const float*)d_in[20]; const float* v3  = (const float*)d_in[21];
    const float* Wk4 = (const float*)d_in[22]; const float* Wr4 = (const float*)d_in[23];
    const float* b4  = (const float*)d_in[24];
    const float* g4  = (const float*)d_in[25]; const float* be4 = (const float*)d_in[26];
    const float* m4  = (const float*)d_in[27]; const float* v4  = (const float*)d_in[28];
    const float* Wd  = (const float*)d_in[29]; const float* bd  = (const float*)d_in[30];

    unsigned short* ws = (unsigned short*)d_ws;

    pack_kernel<<<dim3(N_FRAGS), dim3(64), 0, stream>>>(Wk1, Wr1, Wk2, Wr2, Wk3, Wr3,
                                                        Wk4, Wr4, Wd, ws);
    lstm_ae_mfma<<<dim3(NBLK), dim3(NTH), 0, stream>>>(
        x, b1, b2, b3, b4, bd,
        g1, be1, m1, v1, g2, be2, m2, v2,
        g3, be3, m3, v3, g4, be4, m4, v4,
        (const unsigned short*)ws, (float*)d_out);
}

// Round 4
// 841.247 us; speedup vs baseline: 4.7550x; 1.0219x over previous
//
#include <hip/hip_runtime.h>
#include <math.h>

// LSTM autoencoder, MFMA with register-PINNED bf16 weights.
// 128 blocks x 512 threads (8 waves), BT=16 rows/block.
// R4: weights pinned in VGPRs via asm fences (R3's compiler re-loaded them
// from memory every step at VGPR_Count=124); encoder 3->2 barriers; truncated
// lo-half conversions.

typedef __attribute__((ext_vector_type(8))) short short8;
typedef __attribute__((ext_vector_type(4))) float floatx4;

#define TT 128
#define NF 8
#define BT 16
#define NBLK 128
#define NTH 512

// packed-fragment start indices (in 1024-ushort frag units); hi at +0, lo at +512
#define FS_Z1 0     // K'=160 (Wr1 128 | Wk1 8 | pad), N=512 : 32 tiles x 5 ks
#define FS_Z2 160   // K'=192 (Wk2 128 | Wr2 64),     N=256 : 16 x 6
#define FS_X3 256   // K =64  (Wk3),                  N=256 : 16 x 2
#define FS_Z3 288   // K =64  (Wr3),                  N=256 : 16 x 2
#define FS_Z4 320   // K'=192 (Wk4 64 | Wr4 128),     N=512 : 32 x 6
#define FS_DN 512   // K =128 (Wd), N=16 (cols 8-15 zero) : 1 x 4
#define N_FRAGS 516

#define MFMA(a,b,c) __builtin_amdgcn_mfma_f32_16x16x32_bf16((a),(b),(c),0,0,0)
#define PIN(v) asm volatile("" : "+v"(v))

__device__ __forceinline__ unsigned short bf16hi(float x){
    unsigned u = __float_as_uint(x);
    u += 0x7fffu + ((u >> 16) & 1u);
    return (unsigned short)(u >> 16);
}
__device__ __forceinline__ unsigned short bf16tr(float x){   // truncate (lo halves)
    return (unsigned short)(__float_as_uint(x) >> 16);
}
__device__ __forceinline__ float bf16f(unsigned short h){
    return __uint_as_float(((unsigned)h) << 16);
}
__device__ __forceinline__ float sigmoid_(float x){ return 1.0f/(1.0f+__expf(-x)); }
__device__ __forceinline__ float selu_(float x){
    const float alpha = 1.6732632423543772f, scale = 1.0507009873554805f;
    return x > 0.0f ? scale*x : scale*alpha*(__expf(x)-1.0f);
}

// ---------------- pack kernel: weights -> B-fragment order, bf16 hi/lo ------
__global__ void pack_kernel(const float* __restrict__ Wk1, const float* __restrict__ Wr1,
                            const float* __restrict__ Wk2, const float* __restrict__ Wr2,
                            const float* __restrict__ Wk3, const float* __restrict__ Wr3,
                            const float* __restrict__ Wk4, const float* __restrict__ Wr4,
                            const float* __restrict__ Wd, unsigned short* __restrict__ ws)
{
    const int g = blockIdx.x;
    const int l = threadIdx.x;
    int blob, fs, KS;
    if      (g < FS_Z2){ blob = 0; fs = FS_Z1; KS = 5; }
    else if (g < FS_X3){ blob = 1; fs = FS_Z2; KS = 6; }
    else if (g < FS_Z3){ blob = 2; fs = FS_X3; KS = 2; }
    else if (g < FS_Z4){ blob = 3; fs = FS_Z3; KS = 2; }
    else if (g < FS_DN){ blob = 4; fs = FS_Z4; KS = 6; }
    else               { blob = 5; fs = FS_DN; KS = 4; }
    const int fl = g - fs;
    const int tile = fl / KS, kk = fl % KS;
    const int col = tile * 16 + (l & 15);
    const int k0  = kk * 32 + (l >> 4) * 8;

    short8 hi8, lo8;
    #pragma unroll
    for (int j = 0; j < 8; ++j){
        const int k = k0 + j;
        float v = 0.0f;
        switch (blob){
            case 0: v = (k < 128) ? Wr1[k*512 + col] : (k < 136 ? Wk1[(k-128)*512 + col] : 0.0f); break;
            case 1: v = (k < 128) ? Wk2[k*256 + col] : Wr2[(k-128)*256 + col]; break;
            case 2: v = Wk3[k*256 + col]; break;
            case 3: v = Wr3[k*256 + col]; break;
            case 4: v = (k < 64) ? Wk4[k*512 + col] : Wr4[(k-64)*512 + col]; break;
            case 5: v = (col < 8) ? Wd[k*8 + col] : 0.0f; break;
        }
        unsigned short h = bf16hi(v);
        unsigned short lo = bf16hi(v - bf16f(h));
        hi8[j] = (short)h; lo8[j] = (short)lo;
    }
    *(short8*)(ws + (size_t)g*1024 + l*8)       = hi8;
    *(short8*)(ws + (size_t)g*1024 + 512 + l*8) = lo8;
}

// ---------------- main kernel ------------------------------------------------
__global__ __launch_bounds__(NTH, 1) void lstm_ae_mfma(
    const float* __restrict__ x,
    const float* __restrict__ b1, const float* __restrict__ b2,
    const float* __restrict__ b3, const float* __restrict__ b4,
    const float* __restrict__ bd,
    const float* __restrict__ g1, const float* __restrict__ be1, const float* __restrict__ m1, const float* __restrict__ v1,
    const float* __restrict__ g2, const float* __restrict__ be2, const float* __restrict__ m2, const float* __restrict__ v2,
    const float* __restrict__ g3, const float* __restrict__ be3, const float* __restrict__ m3, const float* __restrict__ v3,
    const float* __restrict__ g4, const float* __restrict__ be4, const float* __restrict__ m4, const float* __restrict__ v4,
    const unsigned short* __restrict__ WS,
    float* __restrict__ out)
{
    // A-fragment planes: [hi/lo][kk][lane*8 + j], lane = (kq<<4)|m
    __shared__ __align__(16) short AZ1[2][2][5][512];
    __shared__ __align__(16) short AH1B[2][4][512];
    __shared__ __align__(16) short AH2[2][2][2][512];
    __shared__ __align__(16) short AH3[2][2][2][512];
    __shared__ __align__(16) short AH3B[2][2][512];
    __shared__ __align__(16) short AH4[2][2][4][512];
    __shared__ __align__(16) short AH4B[2][4][512];
    __shared__ __align__(16) float ZSC[16*260];

    const int tid = threadIdx.x;
    const int w = tid >> 6, l = tid & 63;
    const int l15 = l & 15, q = l >> 4;
    const int b0 = blockIdx.x * BT;

    // ---- per-lane constants ----
    const int u1 = 16*w + l15;
    const float s1v = g1[u1]*rsqrtf(v1[u1]+1e-3f), t1v = be1[u1]-m1[u1]*s1v;
    const float s4v = g4[u1]*rsqrtf(v4[u1]+1e-3f), t4v = be4[u1]-m4[u1]*s4v;
    const int kk1 = u1 >> 5;
    const int sbase1 = ((u1>>3)&3)*128 + (u1&7);

    const int c2row = l15;
    int   kk2[2], s2i[2];
    float s2r[2], t2r[2], s3r[2], t3r[2];
    int u2k[2];
    #pragma unroll
    for (int k2 = 0; k2 < 2; ++k2){
        const int u = (l>>4) + 4*w + 32*k2;
        u2k[k2] = u;
        kk2[k2] = u >> 5;
        s2i[k2] = (((u>>3)&3)*16 + c2row)*8 + (u&7);
        float s2 = g2[u]*rsqrtf(v2[u]+1e-3f); s2r[k2]=s2; t2r[k2]=be2[u]-m2[u]*s2;
        float s3 = g3[u]*rsqrtf(v3[u]+1e-3f); s3r[k2]=s3; t3r[k2]=be3[u]-m3[u]*s3;
    }

    float z1b[4], z4b[4], z2b[2], b3v[2];
    #pragma unroll
    for (int i = 0; i < 4; ++i){
        z1b[i] = b1[(w + 8*i)*16 + l15];
        z4b[i] = b4[(w + 8*i)*16 + l15];
    }
    #pragma unroll
    for (int i = 0; i < 2; ++i){
        z2b[i] = b2[32*w + 16*i + l15];
        b3v[i] = b3[32*w + 16*i + l15];
    }
    const float bdv = (w == 0 && l15 < 8) ? bd[l15] : 0.0f;

    // ---- stationary encoder weights (hi halves), pinned in VGPRs ----
    short8 wz1[4][5], wz2[2][6];
    #pragma unroll
    for (int i = 0; i < 4; ++i)
        #pragma unroll
        for (int kk = 0; kk < 5; ++kk){
            wz1[i][kk] = *(const short8*)(WS + (size_t)(FS_Z1 + (w+8*i)*5 + kk)*1024 + l*8);
            PIN(wz1[i][kk]);
        }
    #pragma unroll
    for (int i = 0; i < 2; ++i)
        #pragma unroll
        for (int kk = 0; kk < 6; ++kk){
            wz2[i][kk] = *(const short8*)(WS + (size_t)(FS_Z2 + (2*w+i)*6 + kk)*1024 + l*8);
            PIN(wz2[i][kk]);
        }

    // ---- prologue: zero t=0 state planes, stage x[0] ----
    for (int i = tid; i < 5120; i += NTH) ((int*)AZ1)[i] = 0;
    for (int i = tid; i < 1024; i += NTH){ ((int*)AH2[0])[i] = 0; ((int*)AH3[0])[i] = 0; }
    for (int i = tid; i < 2048; i += NTH) ((int*)AH4[0])[i] = 0;
    if (tid < 128){
        int row = tid >> 3, j = tid & 7;
        float xv = x[(size_t)(b0+row)*(TT*NF) + j];
        unsigned short xh = bf16hi(xv);
        AZ1[0][0][4][row*8+j] = (short)xh;
        AZ1[0][1][4][row*8+j] = (short)bf16tr(xv - bf16f(xh));
    }
    float c1r[4] = {0,0,0,0}, c4r[4] = {0,0,0,0};
    float c2r[2] = {0,0}, c3r[2] = {0,0};
    __syncthreads();

    // ===================== encoder (2 barriers/step) =====================
    int p = 0;
    for (int t = 0; t < TT; ++t){
        // prefetch next x
        float xnext = 0.0f;
        if (tid < 128 && t+1 < TT)
            xnext = x[(size_t)(b0+(tid>>3))*(TT*NF) + (size_t)(t+1)*NF + (tid&7)];

        // --- z1 (all waves, 4 tiles each) ---
        floatx4 acc[4];
        #pragma unroll
        for (int i = 0; i < 4; ++i) acc[i] = (floatx4){z1b[i],z1b[i],z1b[i],z1b[i]};
        #pragma unroll
        for (int kk = 0; kk < 5; ++kk){
            short8 ah = *(const short8*)&AZ1[p][0][kk][l*8];
            short8 al = *(const short8*)&AZ1[p][1][kk][l*8];
            #pragma unroll
            for (int i = 0; i < 4; ++i){
                acc[i] = MFMA(ah, wz1[i][kk], acc[i]);
                acc[i] = MFMA(al, wz1[i][kk], acc[i]);
            }
        }
        // --- cell1 + BN1 ---
        #pragma unroll
        for (int r = 0; r < 4; ++r){
            const int row = q*4 + r;
            float ig = sigmoid_(acc[0][r]);
            float fg = sigmoid_(acc[1][r]);
            float gg = selu_(acc[2][r]);
            float og = sigmoid_(acc[3][r]);
            float c = fg*c1r[r] + ig*gg; c1r[r] = c;
            float h = og*selu_(c);
            float hb = h*s1v + t1v;
            const int s = sbase1 + row*8;
            unsigned short hh = bf16hi(h);
            AZ1[p^1][0][kk1][s] = (short)hh;
            AZ1[p^1][1][kk1][s] = (short)bf16tr(h - bf16f(hh));
            unsigned short bh_ = bf16hi(hb);
            AH1B[0][kk1][s] = (short)bh_;
            AH1B[1][kk1][s] = (short)bf16tr(hb - bf16f(bh_));
        }
        if (tid < 128 && t+1 < TT){
            int row = tid >> 3, j = tid & 7;
            unsigned short xh = bf16hi(xnext);
            AZ1[p^1][0][4][row*8+j] = (short)xh;
            AZ1[p^1][1][4][row*8+j] = (short)bf16tr(xnext - bf16f(xh));
        }
        __syncthreads();

        // --- z2 (all waves, 2 tiles each) -> scratch ---
        floatx4 a2[2];
        #pragma unroll
        for (int i = 0; i < 2; ++i) a2[i] = (floatx4){z2b[i],z2b[i],z2b[i],z2b[i]};
        #pragma unroll
        for (int kk = 0; kk < 6; ++kk){
            short8 ah, al;
            if (kk < 4){ ah = *(const short8*)&AH1B[0][kk][l*8];   al = *(const short8*)&AH1B[1][kk][l*8]; }
            else       { ah = *(const short8*)&AH2[p][0][kk-4][l*8]; al = *(const short8*)&AH2[p][1][kk-4][l*8]; }
            #pragma unroll
            for (int i = 0; i < 2; ++i){
                a2[i] = MFMA(ah, wz2[i][kk], a2[i]);
                a2[i] = MFMA(al, wz2[i][kk], a2[i]);
            }
        }
        #pragma unroll
        for (int i = 0; i < 2; ++i)
            #pragma unroll
            for (int r = 0; r < 4; ++r)
                ZSC[(q*4+r)*260 + 32*w + 16*i + l15] = a2[i][r];
        __syncthreads();

        // --- cell2 (no trailing barrier; next-step B1 orders reuse) ---
        #pragma unroll
        for (int k2 = 0; k2 < 2; ++k2){
            const int u = u2k[k2];
            const float* zr = &ZSC[c2row*260];
            float ig = sigmoid_(zr[u]);
            float fg = sigmoid_(zr[64+u]);
            float gg = selu_(zr[128+u]);
            float og = sigmoid_(zr[192+u]);
            float c = fg*c2r[k2] + ig*gg; c2r[k2] = c;
            float h = og*selu_(c);
            unsigned short hh = bf16hi(h);
            AH2[p^1][0][kk2[k2]][s2i[k2]] = (short)hh;
            AH2[p^1][1][kk2[k2]][s2i[k2]] = (short)bf16tr(h - bf16f(hh));
        }
        p ^= 1;
    }
    __syncthreads();

    // ===================== bottleneck =====================
    #pragma unroll
    for (int k2 = 0; k2 < 2; ++k2){
        float h2v = bf16f((unsigned short)AH2[p][0][kk2[k2]][s2i[k2]])
                  + bf16f((unsigned short)AH2[p][1][kk2[k2]][s2i[k2]]);
        float e = h2v*s2r[k2] + t2r[k2];
        unsigned short eh = bf16hi(e);
        AH3B[0][kk2[k2]][s2i[k2]] = (short)eh;
        AH3B[1][kk2[k2]][s2i[k2]] = (short)bf16tr(e - bf16f(eh));
    }
    __syncthreads();
    // xz3 = b3 + enc@Wk3 (one-time, streamed hi/lo B)
    floatx4 xz3r[2];
    #pragma unroll
    for (int i = 0; i < 2; ++i) xz3r[i] = (floatx4){b3v[i],b3v[i],b3v[i],b3v[i]};
    #pragma unroll
    for (int kk = 0; kk < 2; ++kk){
        short8 ah = *(const short8*)&AH3B[0][kk][l*8];
        short8 al = *(const short8*)&AH3B[1][kk][l*8];
        #pragma unroll
        for (int i = 0; i < 2; ++i){
            const unsigned short* bp = WS + (size_t)(FS_X3 + (2*w+i)*2 + kk)*1024;
            short8 bh = *(const short8*)(bp + l*8);
            short8 bl = *(const short8*)(bp + 512 + l*8);
            xz3r[i] = MFMA(ah, bh, xz3r[i]);
            xz3r[i] = MFMA(al, bh, xz3r[i]);
            xz3r[i] = MFMA(ah, bl, xz3r[i]);
        }
    }
    // ---- stationary decoder weights, pinned ----
    short8 wz3[2][2], wz4[4][6], wdn[4];
    #pragma unroll
    for (int i = 0; i < 2; ++i)
        #pragma unroll
        for (int kk = 0; kk < 2; ++kk){
            wz3[i][kk] = *(const short8*)(WS + (size_t)(FS_Z3 + (2*w+i)*2 + kk)*1024 + l*8);
            PIN(wz3[i][kk]);
        }
    #pragma unroll
    for (int i = 0; i < 4; ++i)
        #pragma unroll
        for (int kk = 0; kk < 6; ++kk){
            wz4[i][kk] = *(const short8*)(WS + (size_t)(FS_Z4 + (w+8*i)*6 + kk)*1024 + l*8);
            PIN(wz4[i][kk]);
        }
    if (w == 0){
        #pragma unroll
        for (int kk = 0; kk < 4; ++kk){
            wdn[kk] = *(const short8*)(WS + (size_t)(FS_DN + kk)*1024 + l*8);
            PIN(wdn[kk]);
        }
    }

    // ===================== decoder =====================
    p = 0;
    for (int t = 0; t < TT; ++t){
        if (w == 0 && t > 0){
            floatx4 ad = (floatx4){bdv,bdv,bdv,bdv};
            #pragma unroll
            for (int kk = 0; kk < 4; ++kk){
                short8 ah = *(const short8*)&AH4B[0][kk][l*8];
                short8 al = *(const short8*)&AH4B[1][kk][l*8];
                ad = MFMA(ah, wdn[kk], ad);
                ad = MFMA(al, wdn[kk], ad);
            }
            if (l15 < 8){
                #pragma unroll
                for (int r = 0; r < 4; ++r)
                    out[(size_t)(b0 + q*4 + r)*(TT*NF) + (size_t)(t-1)*NF + l15] = ad[r];
            }
        }
        floatx4 a3[2];
        #pragma unroll
        for (int i = 0; i < 2; ++i) a3[i] = xz3r[i];
        #pragma unroll
        for (int kk = 0; kk < 2; ++kk){
            short8 ah = *(const short8*)&AH3[p][0][kk][l*8];
            short8 al = *(const short8*)&AH3[p][1][kk][l*8];
            #pragma unroll
            for (int i = 0; i < 2; ++i){
                a3[i] = MFMA(ah, wz3[i][kk], a3[i]);
                a3[i] = MFMA(al, wz3[i][kk], a3[i]);
            }
        }
        #pragma unroll
        for (int i = 0; i < 2; ++i)
            #pragma unroll
            for (int r = 0; r < 4; ++r)
                ZSC[(q*4+r)*260 + 32*w + 16*i + l15] = a3[i][r];
        __syncthreads();

        // --- cell3 + BN3 ---
        #pragma unroll
        for (int k2 = 0; k2 < 2; ++k2){
            const int u = u2k[k2];
            const float* zr = &ZSC[c2row*260];
            float ig = sigmoid_(zr[u]);
            float fg = sigmoid_(zr[64+u]);
            float gg = selu_(zr[128+u]);
            float og = sigmoid_(zr[192+u]);
            float c = fg*c3r[k2] + ig*gg; c3r[k2] = c;
            float h = og*selu_(c);
            float hb = h*s3r[k2] + t3r[k2];
            unsigned short hh = bf16hi(h);
            AH3[p^1][0][kk2[k2]][s2i[k2]] = (short)hh;
            AH3[p^1][1][kk2[k2]][s2i[k2]] = (short)bf16tr(h - bf16f(hh));
            unsigned short bh_ = bf16hi(hb);
            AH3B[0][kk2[k2]][s2i[k2]] = (short)bh_;
            AH3B[1][kk2[k2]][s2i[k2]] = (short)bf16tr(hb - bf16f(bh_));
        }
        __syncthreads();

        // --- z4 + cell4 + BN4 ---
        floatx4 a4[4];
        #pragma unroll
        for (int i = 0; i < 4; ++i) a4[i] = (floatx4){z4b[i],z4b[i],z4b[i],z4b[i]};
        #pragma unroll
        for (int kk = 0; kk < 6; ++kk){
            short8 ah, al;
            if (kk < 2){ ah = *(const short8*)&AH3B[0][kk][l*8];     al = *(const short8*)&AH3B[1][kk][l*8]; }
            else       { ah = *(const short8*)&AH4[p][0][kk-2][l*8]; al = *(const short8*)&AH4[p][1][kk-2][l*8]; }
            #pragma unroll
            for (int i = 0; i < 4; ++i){
                a4[i] = MFMA(ah, wz4[i][kk], a4[i]);
                a4[i] = MFMA(al, wz4[i][kk], a4[i]);
            }
        }
        #pragma unroll
        for (int r = 0; r < 4; ++r){
            const int row = q*4 + r;
            float ig = sigmoid_(a4[0][r]);
            float fg = sigmoid_(a4[1][r]);
            float gg = selu_(a4[2][r]);
            float og = sigmoid_(a4[3][r]);
            float c = fg*c4r[r] + ig*gg; c4r[r] = c;
            float h = og*selu_(c);
            float hb = h*s4v + t4v;
            const int s = sbase1 + row*8;
            unsigned short hh = bf16hi(h);
            AH4[p^1][0][kk1][s] = (short)hh;
            AH4[p^1][1][kk1][s] = (short)bf16tr(h - bf16f(hh));
            unsigned short bh_ = bf16hi(hb);
            AH4B[0][kk1][s] = (short)bh_;
            AH4B[1][kk1][s] = (short)bf16tr(hb - bf16f(bh_));
        }
        __syncthreads();
        p ^= 1;
    }

    // epilogue: dense for t = TT-1
    if (w == 0){
        floatx4 ad = (floatx4){bdv,bdv,bdv,bdv};
        #pragma unroll
        for (int kk = 0; kk < 4; ++kk){
            short8 ah = *(const short8*)&AH4B[0][kk][l*8];
            short8 al = *(const short8*)&AH4B[1][kk][l*8];
            ad = MFMA(ah, wdn[kk], ad);
            ad = MFMA(al, wdn[kk], ad);
        }
        if (l15 < 8){
            #pragma unroll
            for (int r = 0; r < 4; ++r)
                out[(size_t)(b0 + q*4 + r)*(TT*NF) + (size_t)(TT-1)*NF + l15] = ad[r];
        }
    }
}

extern "C" void kernel_launch(void* const* d_in, const int* in_sizes, int n_in,
                              void* d_out, int out_size, void* d_ws, size_t ws_size,
                              hipStream_t stream) {
    const float* x   = (const float*)d_in[0];
    const float* Wk1 = (const float*)d_in[1];  const float* Wr1 = (const float*)d_in[2];
    const float* b1  = (const float*)d_in[3];
    const float* g1  = (const float*)d_in[4];  const float* be1 = (const float*)d_in[5];
    const float* m1  = (const float*)d_in[6];  const float* v1  = (const float*)d_in[7];
    const float* Wk2 = (const float*)d_in[8];  const float* Wr2 = (const float*)d_in[9];
    const float* b2  = (const float*)d_in[10];
    const float* g2  = (const float*)d_in[11]; const float* be2 = (const float*)d_in[12];
    const float* m2  = (const float*)d_in[13]; const float* v2  = (const float*)d_in[14];
    const float* Wk3 = (const float*)d_in[15]; const float* Wr3 = (const float*)d_in[16];
    const float* b3  = (const float*)d_in[17];
    const float* g3  = (const float*)d_in[18]; const float* be3 = (const float*)d_in[19];
    const float* m3  = (const float*)d_in[20]; const float* v3  = (const float*)d_in[21];
    const float* Wk4 = (const float*)d_in[22]; const float* Wr4 = (const float*)d_in[23];
    const float* b4  = (const float*)d_in[24];
    const float* g4  = (const float*)d_in[25]; const float* be4 = (const float*)d_in[26];
    const float* m4  = (const float*)d_in[27]; const float* v4  = (const float*)d_in[28];
    const float* Wd  = (const float*)d_in[29]; const float* bd  = (const float*)d_in[30];

    unsigned short* ws = (unsigned short*)d_ws;

    pack_kernel<<<dim3(N_FRAGS), dim3(64), 0, stream>>>(Wk1, Wr1, Wk2, Wr2, Wk3, Wr3,
                                                        Wk4, Wr4, Wd, ws);
    lstm_ae_mfma<<<dim3(NBLK), dim3(NTH), 0, stream>>>(
        x, b1, b2, b3, b4, bd,
        g1, be1, m1, v1, g2, be2, m2, v2,
        g3, be3, m3, v3, g4, be4, m4, v4,
        (const unsigned short*)ws, (float*)d_out);
}